// Round 1
// baseline (180.344 us; speedup 1.0000x reference)
//
#include <hip/hip_runtime.h>
#include <math.h>

// Problem constants (from reference):
//   TMIN=0, TMAX=64, SHIFT=8 -> T = 80, t_emb = w (w in [0,65))
//   B=8, S=4096, nOut=8, nIn=8, nBasis=17 -> 8 harmonics, 16 basis fns
//   out[b,o,i,w,s] = a[b,s] * (const0*coefs[o,i,0]
//                              + sum_n basis[b,w,s,n] * norm * coefs[o,i,1+n])
//   basis interleaved: [sin(1t),cos(1t),sin(2t),cos(2t),...], t = (2pi/T)*c*(w-b)

constexpr int S_LEN = 4096;
constexpr int W_LEN = 65;
constexpr int NOI   = 64;   // nOut * nIn
constexpr int NB    = 16;   // 2 * maxN
constexpr int NCOEF = 17;

__global__ __launch_bounds__(256)
void fourier_basis_trf_kernel(const float* __restrict__ a,
                              const float* __restrict__ b,
                              const float* __restrict__ c,
                              const float* __restrict__ coefs,
                              float* __restrict__ out)
{
    __shared__ float s_dc[NOI];
    __shared__ float s_cw[NOI][NB];

    const int tid = threadIdx.x;

    // Stage coefs into LDS with constants pre-folded:
    //   s_dc[oi]    = coefs[oi,0]   / sqrt(80)
    //   s_cw[oi][n] = coefs[oi,1+n] / sqrt(40)
    for (int idx = tid; idx < NOI * NCOEF; idx += 256) {
        const int oi = idx / NCOEF;
        const int k  = idx - oi * NCOEF;
        const float v = coefs[idx];
        if (k == 0) s_dc[oi]        = v * 0.11180339887498948f;  // 1/sqrt(80)
        else        s_cw[oi][k - 1] = v * 0.15811388300841897f;  // 1/sqrt(40)
    }
    __syncthreads();

    // Block decomposition: 4 blocks per (b,w) row; each thread does 4 s.
    const int blk    = blockIdx.x;
    const int schunk = blk & 3;
    const int rest   = blk >> 2;        // = b*W_LEN + w
    const int w      = rest % W_LEN;
    const int bb     = rest / W_LEN;
    const int s0     = (schunk * 256 + tid) * 4;

    const int abi = bb * S_LEN + s0;
    const float4 av = *reinterpret_cast<const float4*>(a + abi);
    const float4 bv = *reinterpret_cast<const float4*>(b + abi);
    const float4 cv = *reinterpret_cast<const float4*>(c + abi);

    const float tf = (float)w;  // TMIN = 0
    const float K  = 6.283185307179586f / 80.0f;  // 2*pi/T

    // basis[n][j]: basis value n for s-position j (raw sin/cos; norm folded
    // into s_cw). Built with one sincosf + angle-addition recurrence.
    float bas[NB][4];
    {
        const float xj[4] = { cv.x * (tf - bv.x), cv.y * (tf - bv.y),
                              cv.z * (tf - bv.z), cv.w * (tf - bv.w) };
        #pragma unroll
        for (int j = 0; j < 4; ++j) {
            float sn, cs;
            sincosf(K * xj[j], &sn, &cs);
            bas[0][j] = sn;
            bas[1][j] = cs;
            float sk = sn, ck = cs;
            #pragma unroll
            for (int k = 1; k < 8; ++k) {
                const float s2 = fmaf(sk, cs,  ck * sn);
                const float c2 = fmaf(ck, cs, -sk * sn);
                bas[2 * k][j]     = s2;
                bas[2 * k + 1][j] = c2;
                sk = s2;
                ck = c2;
            }
        }
    }

    // out flat index: (((bb*8+o)*8+i)*65 + w)*4096 + s ; oi = o*8+i
    float* outp = out + ((size_t)bb * NOI * W_LEN + w) * S_LEN + s0;
    constexpr size_t OI_STRIDE = (size_t)W_LEN * S_LEN;  // 266240

    #pragma unroll 4
    for (int oi = 0; oi < NOI; ++oi) {
        const float d = s_dc[oi];
        float ax = d, ay = d, az = d, aw = d;
        #pragma unroll
        for (int n = 0; n < NB; ++n) {
            const float cn = s_cw[oi][n];
            ax = fmaf(bas[n][0], cn, ax);
            ay = fmaf(bas[n][1], cn, ay);
            az = fmaf(bas[n][2], cn, az);
            aw = fmaf(bas[n][3], cn, aw);
        }
        const float4 r = make_float4(ax * av.x, ay * av.y, az * av.z, aw * av.w);
        *reinterpret_cast<float4*>(outp + (size_t)oi * OI_STRIDE) = r;
    }
}

extern "C" void kernel_launch(void* const* d_in, const int* in_sizes, int n_in,
                              void* d_out, int out_size, void* d_ws, size_t ws_size,
                              hipStream_t stream)
{
    const float* a     = (const float*)d_in[0];
    const float* b     = (const float*)d_in[1];
    const float* c     = (const float*)d_in[2];
    const float* coefs = (const float*)d_in[3];
    float* out = (float*)d_out;

    // grid: B * W * (S / (4*256)) = 8 * 65 * 4 = 2080 blocks
    const dim3 grid(8 * W_LEN * 4);
    const dim3 block(256);
    fourier_basis_trf_kernel<<<grid, block, 0, stream>>>(a, b, c, coefs, out);
}

// Round 2
// 114.920 us; speedup vs baseline: 1.5693x; 1.5693x over previous
//
#include <hip/hip_runtime.h>
#include <math.h>

// FourierBasisTRF: out[b,o,i,w,s] = a[b,s] * ( coefs[o,i,0]*const0
//                    + sum_n basis_n(b,w,s) * norm * coefs[o,i,1+n] )
// T=80, t_emb=w (w in [0,65)), basis interleaved [sin(1t),cos(1t),sin(2t),...],
// t = (2*pi/80) * c[b,s] * (w - b[b,s]).
// Algebra used here: const0 = norm/sqrt(2), so
//   out = (a*norm) * ( coefs[oi,0]/sqrt(2) + sum_n coefs[oi,1+n]*bas_n )
//
// Design notes (R2):
//  - No LDS: coefs reads are wave-uniform -> compiler emits s_load; FMA takes
//    the coef as an SGPR operand. Removes the LDS pipe from the inner loop.
//  - 2 s-positions per thread (float2): bas[16][2]=32 VGPR, targeting ~64-72
//    total VGPR -> 7-8 waves/SIMD for store/latency overlap.
//  - Stores: global_store_dwordx2, 64 lanes x 8B = 512B contiguous per instr.

constexpr int S_LEN = 4096;
constexpr int W_LEN = 65;
constexpr int NOI   = 64;   // nOut * nIn
constexpr int NB    = 16;   // 2 * maxN
constexpr int NCOEF = 17;

using f2 = __attribute__((ext_vector_type(2))) float;

__global__ __launch_bounds__(256)
void fourier_basis_trf_kernel(const float* __restrict__ a,
                              const float* __restrict__ b,
                              const float* __restrict__ c,
                              const float* __restrict__ coefs,
                              float* __restrict__ out)
{
    const int tid    = threadIdx.x;
    const int blk    = blockIdx.x;
    const int schunk = blk & 7;          // 8 chunks of 512 s per (b,w) row
    const int rest   = blk >> 3;         // = bb*W_LEN + w
    const int w      = rest % W_LEN;
    const int bb     = rest / W_LEN;
    const int s0     = (schunk * 256 + tid) * 2;

    const int abi = bb * S_LEN + s0;
    const f2 av = *reinterpret_cast<const f2*>(a + abi);
    const f2 bv = *reinterpret_cast<const f2*>(b + abi);
    const f2 cv = *reinterpret_cast<const f2*>(c + abi);

    const float tf   = (float)w;                      // TMIN = 0
    const float K    = 6.283185307179586f / 80.0f;    // 2*pi/T
    const float NORM = 0.15811388300841897f;          // 1/sqrt(40)
    const float RS2  = 0.7071067811865476f;           // 1/sqrt(2)

    const float a0 = av.x * NORM;
    const float a1 = av.y * NORM;

    // Raw sin/cos harmonics (norm folded into a0/a1 above).
    float bas[NB][2];
    {
        const float xv[2] = { cv.x * (tf - bv.x), cv.y * (tf - bv.y) };
        #pragma unroll
        for (int j = 0; j < 2; ++j) {
            float sn, cs;
            sincosf(K * xv[j], &sn, &cs);
            bas[0][j] = sn;
            bas[1][j] = cs;
            float sk = sn, ck = cs;
            #pragma unroll
            for (int k = 1; k < 8; ++k) {
                const float s2 = fmaf(sk, cs,  ck * sn);
                const float c2 = fmaf(ck, cs, -sk * sn);
                bas[2 * k][j]     = s2;
                bas[2 * k + 1][j] = c2;
                sk = s2;
                ck = c2;
            }
        }
    }

    // out flat index: (((bb*8+o)*8+i)*65 + w)*4096 + s ; oi = o*8+i
    float* outp = out + ((size_t)bb * NOI * W_LEN + w) * S_LEN + s0;
    constexpr size_t OI_STRIDE = (size_t)W_LEN * S_LEN;  // 266240

    #pragma unroll 2
    for (int oi = 0; oi < NOI; ++oi) {
        const float* cw = coefs + oi * NCOEF;   // wave-uniform -> s_load
        const float d = cw[0] * RS2;
        float x0 = d, x1 = d;
        #pragma unroll
        for (int n = 0; n < NB; ++n) {
            const float cn = cw[1 + n];
            x0 = fmaf(bas[n][0], cn, x0);
            x1 = fmaf(bas[n][1], cn, x1);
        }
        f2 r;
        r.x = x0 * a0;
        r.y = x1 * a1;
        *reinterpret_cast<f2*>(outp + (size_t)oi * OI_STRIDE) = r;
    }
}

extern "C" void kernel_launch(void* const* d_in, const int* in_sizes, int n_in,
                              void* d_out, int out_size, void* d_ws, size_t ws_size,
                              hipStream_t stream)
{
    const float* a     = (const float*)d_in[0];
    const float* b     = (const float*)d_in[1];
    const float* c     = (const float*)d_in[2];
    const float* coefs = (const float*)d_in[3];
    float* out = (float*)d_out;

    // grid: B * W * (S / (2*256)) = 8 * 65 * 8 = 4160 blocks
    const dim3 grid(8 * W_LEN * 8);
    const dim3 block(256);
    fourier_basis_trf_kernel<<<grid, block, 0, stream>>>(a, b, c, coefs, out);
}

// Round 4
// 110.815 us; speedup vs baseline: 1.6274x; 1.0370x over previous
//
#include <hip/hip_runtime.h>
#include <math.h>

// FourierBasisTRF: out[b,o,i,w,s] = a[b,s] * ( coefs[o,i,0]*const0
//                    + sum_n basis_n(b,w,s) * norm * coefs[o,i,1+n] )
// T=80, t_emb=w (w in [0,65)), basis interleaved [sin(1t),cos(1t),sin(2t),...],
// t = (2*pi/80) * c[b,s] * (w - b[b,s]).
// Algebra: const0 = norm/sqrt(2) ->
//   out = (a*norm) * ( coefs[oi,0]/sqrt(2) + sum_n coefs[oi,1+n]*bas_n )
//
// R4 = R3 with the compile fix: __builtin_nontemporal_store requires an
// ext_vector_type pointer, not HIP's float4 class. Everything else identical.
//  - No LDS; coefs reads wave-uniform -> s_load, FMA takes SGPR operand.
//  - 4 s-positions/thread: float4 nontemporal stores (global_store_dwordx4 nt)
//    = 1 KB/wave/burst, half the store instrs per byte vs R2, no L2 pollution.

constexpr int S_LEN = 4096;
constexpr int W_LEN = 65;
constexpr int NOI   = 64;   // nOut * nIn
constexpr int NB    = 16;   // 2 * maxN
constexpr int NCOEF = 17;

using f4 = __attribute__((ext_vector_type(4))) float;

__global__ __launch_bounds__(256)
void fourier_basis_trf_kernel(const float* __restrict__ a,
                              const float* __restrict__ b,
                              const float* __restrict__ c,
                              const float* __restrict__ coefs,
                              float* __restrict__ out)
{
    const int tid    = threadIdx.x;
    const int blk    = blockIdx.x;
    const int schunk = blk & 3;          // 4 chunks of 1024 s per (b,w) row
    const int rest   = blk >> 2;         // = bb*W_LEN + w
    const int w      = rest % W_LEN;
    const int bb     = rest / W_LEN;
    const int s0     = (schunk * 256 + tid) * 4;

    const int abi = bb * S_LEN + s0;
    const f4 av = *reinterpret_cast<const f4*>(a + abi);
    const f4 bv = *reinterpret_cast<const f4*>(b + abi);
    const f4 cv = *reinterpret_cast<const f4*>(c + abi);

    const float tf   = (float)w;                      // TMIN = 0
    const float K    = 6.283185307179586f / 80.0f;    // 2*pi/T
    const float NORM = 0.15811388300841897f;          // 1/sqrt(40)
    const float RS2  = 0.7071067811865476f;           // 1/sqrt(2)

    const float a0 = av.x * NORM;
    const float a1 = av.y * NORM;
    const float a2 = av.z * NORM;
    const float a3 = av.w * NORM;

    // Raw sin/cos harmonics (norm folded into a0..a3).
    float bas[NB][4];
    {
        const float xv[4] = { cv.x * (tf - bv.x), cv.y * (tf - bv.y),
                              cv.z * (tf - bv.z), cv.w * (tf - bv.w) };
        #pragma unroll
        for (int j = 0; j < 4; ++j) {
            float sn, cs;
            sincosf(K * xv[j], &sn, &cs);
            bas[0][j] = sn;
            bas[1][j] = cs;
            float sk = sn, ck = cs;
            #pragma unroll
            for (int k = 1; k < 8; ++k) {
                const float s2 = fmaf(sk, cs,  ck * sn);
                const float c2 = fmaf(ck, cs, -sk * sn);
                bas[2 * k][j]     = s2;
                bas[2 * k + 1][j] = c2;
                sk = s2;
                ck = c2;
            }
        }
    }

    // out flat index: (((bb*8+o)*8+i)*65 + w)*4096 + s ; oi = o*8+i
    float* outp = out + ((size_t)bb * NOI * W_LEN + w) * S_LEN + s0;
    constexpr size_t OI_STRIDE = (size_t)W_LEN * S_LEN;  // 266240

    #pragma unroll 2
    for (int oi = 0; oi < NOI; ++oi) {
        const float* cw = coefs + oi * NCOEF;   // wave-uniform -> s_load
        const float d = cw[0] * RS2;
        float x0 = d, x1 = d, x2 = d, x3 = d;
        #pragma unroll
        for (int n = 0; n < NB; ++n) {
            const float cn = cw[1 + n];
            x0 = fmaf(bas[n][0], cn, x0);
            x1 = fmaf(bas[n][1], cn, x1);
            x2 = fmaf(bas[n][2], cn, x2);
            x3 = fmaf(bas[n][3], cn, x3);
        }
        f4 r;
        r.x = x0 * a0;
        r.y = x1 * a1;
        r.z = x2 * a2;
        r.w = x3 * a3;
        __builtin_nontemporal_store(r, reinterpret_cast<f4*>(
            outp + (size_t)oi * OI_STRIDE));
    }
}

extern "C" void kernel_launch(void* const* d_in, const int* in_sizes, int n_in,
                              void* d_out, int out_size, void* d_ws, size_t ws_size,
                              hipStream_t stream)
{
    const float* a     = (const float*)d_in[0];
    const float* b     = (const float*)d_in[1];
    const float* c     = (const float*)d_in[2];
    const float* coefs = (const float*)d_in[3];
    float* out = (float*)d_out;

    // grid: B * W * (S / (4*256)) = 8 * 65 * 4 = 2080 blocks
    const dim3 grid(8 * W_LEN * 4);
    const dim3 block(256);
    fourier_basis_trf_kernel<<<grid, block, 0, stream>>>(a, b, c, coefs, out);
}

// Round 5
// 108.993 us; speedup vs baseline: 1.6546x; 1.0167x over previous
//
#include <hip/hip_runtime.h>
#include <math.h>

// FourierBasisTRF: out[b,o,i,w,s] = a[b,s] * ( coefs[o,i,0]*const0
//                    + sum_n basis_n(b,w,s) * norm * coefs[o,i,1+n] )
// T=80, t_emb=w (w in [0,65)), basis interleaved [sin(1t),cos(1t),sin(2t),...],
// t = (2*pi/80) * c[b,s] * (w - b[b,s]).
// Algebra: const0 = norm/sqrt(2) ->
//   out = (a*norm) * ( coefs[oi,0]/sqrt(2) + sum_n coefs[oi,1+n]*bas_n )
//
// R5 design (L2 write-combining lever):
//  - REMOVE nontemporal: writes flow through the XCD's 4MB L2 (full 64B-line
//    writes -> no allocate-fetch), which aggregates our scattered 4KB bursts
//    into longer sequential eviction runs for HBM row locality.
//  - Chunked XCD swizzle (2080 = 8*260): hardware round-robins blockIdx
//    across 8 XCDs; remap logical = (hw&7)*260 + (hw>>3) so each XCD owns a
//    contiguous 68MB output region (XCD k <-> bb=k). 128 resident blocks per
//    XCD write into their own L2; a/b/c reads become XCD-local too.
//  - Otherwise identical to R4: no LDS, SGPR coefs, 4 s/thread, dwordx4 stores.

constexpr int S_LEN = 4096;
constexpr int W_LEN = 65;
constexpr int NOI   = 64;   // nOut * nIn
constexpr int NB    = 16;   // 2 * maxN
constexpr int NCOEF = 17;

using f4 = __attribute__((ext_vector_type(4))) float;

__global__ __launch_bounds__(256)
void fourier_basis_trf_kernel(const float* __restrict__ a,
                              const float* __restrict__ b,
                              const float* __restrict__ c,
                              const float* __restrict__ coefs,
                              float* __restrict__ out)
{
    const int tid = threadIdx.x;

    // XCD-chunked swizzle: hw blocks round-robin over 8 XCDs; give XCD x the
    // logical range [x*260, (x+1)*260). 2080 = 8*260 exactly (bijective).
    const int hw  = blockIdx.x;
    const int blk = (hw & 7) * 260 + (hw >> 3);

    const int schunk = blk & 3;          // 4 chunks of 1024 s per (b,w) row
    const int rest   = blk >> 2;         // = bb*W_LEN + w
    const int w      = rest % W_LEN;
    const int bb     = rest / W_LEN;
    const int s0     = (schunk * 256 + tid) * 4;

    const int abi = bb * S_LEN + s0;
    const f4 av = *reinterpret_cast<const f4*>(a + abi);
    const f4 bv = *reinterpret_cast<const f4*>(b + abi);
    const f4 cv = *reinterpret_cast<const f4*>(c + abi);

    const float tf   = (float)w;                      // TMIN = 0
    const float K    = 6.283185307179586f / 80.0f;    // 2*pi/T
    const float NORM = 0.15811388300841897f;          // 1/sqrt(40)
    const float RS2  = 0.7071067811865476f;           // 1/sqrt(2)

    const float a0 = av.x * NORM;
    const float a1 = av.y * NORM;
    const float a2 = av.z * NORM;
    const float a3 = av.w * NORM;

    // Raw sin/cos harmonics (norm folded into a0..a3).
    float bas[NB][4];
    {
        const float xv[4] = { cv.x * (tf - bv.x), cv.y * (tf - bv.y),
                              cv.z * (tf - bv.z), cv.w * (tf - bv.w) };
        #pragma unroll
        for (int j = 0; j < 4; ++j) {
            float sn, cs;
            sincosf(K * xv[j], &sn, &cs);
            bas[0][j] = sn;
            bas[1][j] = cs;
            float sk = sn, ck = cs;
            #pragma unroll
            for (int k = 1; k < 8; ++k) {
                const float s2 = fmaf(sk, cs,  ck * sn);
                const float c2 = fmaf(ck, cs, -sk * sn);
                bas[2 * k][j]     = s2;
                bas[2 * k + 1][j] = c2;
                sk = s2;
                ck = c2;
            }
        }
    }

    // out flat index: (((bb*8+o)*8+i)*65 + w)*4096 + s ; oi = o*8+i
    float* outp = out + ((size_t)bb * NOI * W_LEN + w) * S_LEN + s0;
    constexpr size_t OI_STRIDE = (size_t)W_LEN * S_LEN;  // 266240

    #pragma unroll 2
    for (int oi = 0; oi < NOI; ++oi) {
        const float* cw = coefs + oi * NCOEF;   // wave-uniform -> s_load
        const float d = cw[0] * RS2;
        float x0 = d, x1 = d, x2 = d, x3 = d;
        #pragma unroll
        for (int n = 0; n < NB; ++n) {
            const float cn = cw[1 + n];
            x0 = fmaf(bas[n][0], cn, x0);
            x1 = fmaf(bas[n][1], cn, x1);
            x2 = fmaf(bas[n][2], cn, x2);
            x3 = fmaf(bas[n][3], cn, x3);
        }
        f4 r;
        r.x = x0 * a0;
        r.y = x1 * a1;
        r.z = x2 * a2;
        r.w = x3 * a3;
        *reinterpret_cast<f4*>(outp + (size_t)oi * OI_STRIDE) = r;
    }
}

extern "C" void kernel_launch(void* const* d_in, const int* in_sizes, int n_in,
                              void* d_out, int out_size, void* d_ws, size_t ws_size,
                              hipStream_t stream)
{
    const float* a     = (const float*)d_in[0];
    const float* b     = (const float*)d_in[1];
    const float* c     = (const float*)d_in[2];
    const float* coefs = (const float*)d_in[3];
    float* out = (float*)d_out;

    // grid: B * W * (S / (4*256)) = 8 * 65 * 4 = 2080 blocks
    const dim3 grid(8 * W_LEN * 4);
    const dim3 block(256);
    fourier_basis_trf_kernel<<<grid, block, 0, stream>>>(a, b, c, coefs, out);
}